// Round 13
// baseline (208.888 us; speedup 1.0000x reference)
//
#include <hip/hip_runtime.h>
#include <hip/hip_bf16.h>

// ---------------------------------------------------------------------------
// GAT + 2 FC layers, MFMA + atomic-free CSR build (7 launches).
// xpb uses a PERMUTED channel layout (word w of a row = channels
// c0=32(w&3)+(w>>2), c1=c0+16) so g1's MFMA D-fragment stores are coalesced
// int4 writes. k5 consumes the permutation natively; zb inherits it and
// k0 applies the same k-permutation to W_fc1/W_fc2 rows (GEMM is invariant
// to a shared contraction-index permutation).
// k5: lane-specialized scores + 16-deep gather batches (MLP=16).
// ---------------------------------------------------------------------------

#define NBUCK  256
#define BSHIFT 9
#define BNODES 512
#define IPB    8192

typedef __attribute__((ext_vector_type(8))) short bf16x8;
typedef __attribute__((ext_vector_type(4))) float f32x4;

static __device__ __forceinline__ short f2bf(float f) {
    __hip_bfloat16 h = __float2bfloat16(f);
    return *reinterpret_cast<short*>(&h);
}

// ---------------- K0: weight swizzles + WA precompute + col_total zero -------
__global__ __launch_bounds__(256) void k0_swizzle(
    const float* __restrict__ W0, const float* __restrict__ W1,
    const float* __restrict__ W2, const float* __restrict__ att_s,
    const float* __restrict__ att_d, unsigned short* __restrict__ S0,
    unsigned short* __restrict__ S1, unsigned short* __restrict__ S2,
    unsigned short* __restrict__ Sa, int* __restrict__ col_total)
{
    const int t = blockIdx.x * 256 + threadIdx.x;
    if (t < NBUCK) col_total[t] = 0;
    if (t < 3 * 2048) {
        const int m = t >> 11;
        const int r = t & 2047;
        const int tile = r >> 6;          // cb*4 + ks
        const int l    = r & 63;
        const int ks   = tile & 3;
        const int cb   = tile >> 2;
        const int c    = cb * 16 + (l & 15);
        const int kb   = ks * 32 + (l >> 4) * 8;
        const float* W = (m == 0) ? W0 : (m == 1) ? W1 : W2;
        unsigned short* S = (m == 0) ? S0 : (m == 1) ? S1 : S2;
        unsigned short* dst = S + ((size_t)tile * 64 + l) * 8;
#pragma unroll
        for (int j = 0; j < 8; ++j) {
            const int p = kb + j;
            int krow;
            if (m == 0) {
                krow = p;                         // g1: A from x, canonical k
            } else {
                // zb's permuted k-order: word w=p>>1, half hi=p&1
                const int w2 = p >> 1, hi = p & 1;
                krow = 32 * (w2 & 3) + (w2 >> 2) + 16 * hi;
            }
            dst[j] = (unsigned short)f2bf(W[krow * 128 + c]);
        }
    } else if (t < 3 * 2048 + 256) {
        const int r  = t - 3 * 2048;
        const int ks = r >> 6;
        const int l  = r & 63;
        const int hp = l & 15;
        const int h  = hp & 7;
        const float* av = (hp < 8) ? (att_s + h * 16) : (att_d + h * 16);
        unsigned short* dst = Sa + ((size_t)ks * 64 + l) * 8;
#pragma unroll
        for (int j = 0; j < 8; ++j) {
            const int k = ks * 32 + (l >> 4) * 8 + j;
            float acc = 0.f;
#pragma unroll
            for (int u = 0; u < 16; ++u)
                acc += W0[k * 128 + h * 16 + u] * av[u];
            dst[j] = (unsigned short)f2bf(acc);
        }
    }
}

// ---------------- G1P1: fused GEMM+scores | bucket histogram ----------------
__global__ __launch_bounds__(256) void g1p1(
    const float* __restrict__ x, const unsigned short* __restrict__ Wswz,
    const unsigned short* __restrict__ Sa, unsigned short* __restrict__ xpb,
    float* __restrict__ a_src, float* __restrict__ a_dst,
    const int* __restrict__ ei, int* __restrict__ M, int* __restrict__ col_total,
    int n, int E, int g1b, int nblk)
{
    if ((int)blockIdx.x < g1b) {
        const int wid  = __builtin_amdgcn_readfirstlane(threadIdx.x >> 6);
        const int lane = threadIdx.x & 63;
        const int lr   = lane & 15;
        const int kg   = lane >> 4;
        const int rowbase = blockIdx.x * 128 + wid * 32;

        bf16x8 afr[2][4];
#pragma unroll
        for (int rt = 0; rt < 2; ++rt) {
            int row = rowbase + rt * 16 + lr;
            row = (row < n) ? row : (n - 1);
            const float* rp = x + (size_t)row * 128 + kg * 8;
#pragma unroll
            for (int ks = 0; ks < 4; ++ks) {
                const float4 v0 = *reinterpret_cast<const float4*>(rp + ks * 32);
                const float4 v1 = *reinterpret_cast<const float4*>(rp + ks * 32 + 4);
                bf16x8 a;
                a[0] = f2bf(v0.x); a[1] = f2bf(v0.y); a[2] = f2bf(v0.z); a[3] = f2bf(v0.w);
                a[4] = f2bf(v1.x); a[5] = f2bf(v1.y); a[6] = f2bf(v1.z); a[7] = f2bf(v1.w);
                afr[rt][ks] = a;
            }
        }

        f32x4 acc[2][8] = {};
#pragma unroll
        for (int cb = 0; cb < 8; ++cb) {
            const unsigned short* bp = Wswz + ((size_t)(cb * 4) * 64 + lane) * 8;
            bf16x8 bfr[4];
#pragma unroll
            for (int ks = 0; ks < 4; ++ks)
                bfr[ks] = *reinterpret_cast<const bf16x8*>(bp + (size_t)ks * 512);
#pragma unroll
            for (int ks = 0; ks < 4; ++ks) {
                acc[0][cb] = __builtin_amdgcn_mfma_f32_16x16x32_bf16(afr[0][ks], bfr[ks], acc[0][cb], 0, 0, 0);
                acc[1][cb] = __builtin_amdgcn_mfma_f32_16x16x32_bf16(afr[1][ks], bfr[ks], acc[1][cb], 0, 0, 0);
            }
        }

        f32x4 accs[2] = {};
#pragma unroll
        for (int ks = 0; ks < 4; ++ks) {
            const bf16x8 bs = *reinterpret_cast<const bf16x8*>(Sa + ((size_t)ks * 64 + lane) * 8);
            accs[0] = __builtin_amdgcn_mfma_f32_16x16x32_bf16(afr[0][ks], bs, accs[0], 0, 0, 0);
            accs[1] = __builtin_amdgcn_mfma_f32_16x16x32_bf16(afr[1][ks], bs, accs[1], 0, 0, 0);
        }

#pragma unroll
        for (int rt = 0; rt < 2; ++rt) {
#pragma unroll
            for (int reg = 0; reg < 4; ++reg) {
                const int row = rowbase + rt * 16 + kg * 4 + reg;
                if (row < n) {
                    int4 pk;
                    pk.x = (int)(((unsigned)(unsigned short)f2bf(acc[rt][1][reg]) << 16) |
                                  (unsigned)(unsigned short)f2bf(acc[rt][0][reg]));
                    pk.y = (int)(((unsigned)(unsigned short)f2bf(acc[rt][3][reg]) << 16) |
                                  (unsigned)(unsigned short)f2bf(acc[rt][2][reg]));
                    pk.z = (int)(((unsigned)(unsigned short)f2bf(acc[rt][5][reg]) << 16) |
                                  (unsigned)(unsigned short)f2bf(acc[rt][4][reg]));
                    pk.w = (int)(((unsigned)(unsigned short)f2bf(acc[rt][7][reg]) << 16) |
                                  (unsigned)(unsigned short)f2bf(acc[rt][6][reg]));
                    *reinterpret_cast<int4*>(xpb + (size_t)row * 128 + lr * 8) = pk;
                    if (lr < 8) a_src[row * 8 + lr] = accs[rt][reg];
                    else        a_dst[row * 8 + (lr - 8)] = accs[rt][reg];
                }
            }
        }
    } else {
        __shared__ int h[NBUCK];
        const int pb  = blockIdx.x - g1b;
        const int tid = threadIdx.x;
        for (int k = tid; k < NBUCK; k += 256) h[k] = 0;
        __syncthreads();

        const int tot = E + n;
        const int base = pb * IPB;
        const int lim = (base + IPB < tot) ? base + IPB : tot;
        for (int j = base + tid; j < lim; j += 256) {
            const int d = (j < E) ? ei[E + j] : (j - E);
            atomicAdd(&h[d >> BSHIFT], 1);
        }
        __syncthreads();
        for (int k = tid; k < NBUCK; k += 256) {
            M[(size_t)k * nblk + pb] = h[k];
            if (h[k]) atomicAdd(&col_total[k], h[k]);
        }
    }
}

// ---------------- P2a: bucket bases + per-bucket scan of M ----------------
__global__ __launch_bounds__(256) void p2a_colscan(
    int* __restrict__ M, const int* __restrict__ col_total,
    int* __restrict__ bucket_ptr, int* __restrict__ row_ptr, int nblk, int N)
{
    const int b    = blockIdx.x;
    const int tid  = threadIdx.x;
    const int lane = tid & 63;
    const int wid  = tid >> 6;
    __shared__ int wsum[4];
    __shared__ int sbase;

    const int v0 = col_total[tid];
    int ws0 = v0;
#pragma unroll
    for (int off = 1; off < 64; off <<= 1) {
        const int t = __shfl_up(ws0, off);
        if (lane >= off) ws0 += t;
    }
    if (lane == 63) wsum[wid] = ws0;
    __syncthreads();
    int woff0 = 0;
    for (int w2 = 0; w2 < wid; ++w2) woff0 += wsum[w2];
    const int excl0 = woff0 + ws0 - v0;
    if (tid == b) sbase = excl0;
    if (b == NBUCK - 1 && tid == NBUCK - 1) {
        bucket_ptr[NBUCK] = excl0 + v0;
        row_ptr[N] = excl0 + v0;
    }
    __syncthreads();
    const int base = sbase;
    if (tid == 0) bucket_ptr[b] = base;
    __syncthreads();

    int carry = base;
    for (int bb = 0; bb < nblk; bb += 256) {
        const int idx = bb + tid;
        const int v = (idx < nblk) ? M[(size_t)b * nblk + idx] : 0;
        int ws = v;
#pragma unroll
        for (int off = 1; off < 64; off <<= 1) {
            const int t = __shfl_up(ws, off);
            if (lane >= off) ws += t;
        }
        if (lane == 63) wsum[wid] = ws;
        __syncthreads();
        int woff = 0;
        for (int w2 = 0; w2 < wid; ++w2) woff += wsum[w2];
        const int alltot = wsum[0] + wsum[1] + wsum[2] + wsum[3];
        if (idx < nblk) M[(size_t)b * nblk + idx] = carry + woff + ws - v;
        carry += alltot;
        __syncthreads();
    }
}

// ---------------- P3: scatter packed (src | dl<<17) into bucket segments -----
__global__ __launch_bounds__(256) void p3_scatter(
    const int* __restrict__ ei, const int* __restrict__ M,
    int* __restrict__ pairs, int E, int N, int nblk)
{
    __shared__ int lcnt[NBUCK];
    const int tid = threadIdx.x;
    for (int k = tid; k < NBUCK; k += 256) lcnt[k] = 0;
    __syncthreads();

    const int tot = E + N;
    const int base = blockIdx.x * IPB;
    const int lim = (base + IPB < tot) ? base + IPB : tot;
    for (int j = base + tid; j < lim; j += 256) {
        int s, d;
        if (j < E) { s = ei[j]; d = ei[E + j]; }
        else       { s = j - E; d = s; }
        const int b = d >> BSHIFT;
        const int r = atomicAdd(&lcnt[b], 1);
        const int pos = M[(size_t)b * nblk + blockIdx.x] + r;
        pairs[pos] = s | ((d & (BNODES - 1)) << 17);
    }
}

// ---------------- P4: per-bucket row_ptr + csr scatter ----------------
__global__ __launch_bounds__(256) void p4_finalize(
    const int* __restrict__ pairs, const int* __restrict__ bucket_ptr,
    int* __restrict__ row_ptr, int* __restrict__ csr_src, int N)
{
    const int b     = blockIdx.x;
    const int node0 = b << BSHIFT;
    const int beg   = bucket_ptr[b];
    const int end   = bucket_ptr[b + 1];
    const int tid   = threadIdx.x;
    const int lane  = tid & 63;
    const int wid   = tid >> 6;

    __shared__ int hist[BNODES];
    __shared__ int exc[BNODES];
    __shared__ int cnt2[BNODES];
    __shared__ int wsum[4];

    for (int k = tid; k < BNODES; k += 256) { hist[k] = 0; cnt2[k] = 0; }
    __syncthreads();

    for (int i = beg + tid; i < end; i += 256)
        atomicAdd(&hist[pairs[i] >> 17], 1);
    __syncthreads();

    const int a0 = hist[2 * tid];
    const int a1 = hist[2 * tid + 1];
    const int s  = a0 + a1;
    int ws = s;
#pragma unroll
    for (int off = 1; off < 64; off <<= 1) {
        const int t = __shfl_up(ws, off);
        if (lane >= off) ws += t;
    }
    if (lane == 63) wsum[wid] = ws;
    __syncthreads();
    int woff = 0;
    for (int w2 = 0; w2 < wid; ++w2) woff += wsum[w2];
    const int e0 = woff + ws - s;
    exc[2 * tid]     = e0;
    exc[2 * tid + 1] = e0 + a0;
    __syncthreads();

    for (int k = tid; k < BNODES; k += 256) {
        const int node = node0 + k;
        if (node < N) row_ptr[node] = beg + exc[k];
    }
    for (int i = beg + tid; i < end; i += 256) {
        const int v  = pairs[i];
        const int dl = v >> 17;
        const int r  = atomicAdd(&cnt2[dl], 1);
        csr_src[beg + exc[dl] + r] = v & 0x1FFFF;
    }
}

// ---------------- K5: lane-specialized scores, MLP=16, permuted layout -------
__global__ __launch_bounds__(256) void k5_aggregate(
    const unsigned short* __restrict__ xpb, const float* __restrict__ a_src,
    const float* __restrict__ a_dst, const int* __restrict__ row_ptr,
    const int* __restrict__ csr_src, const float* __restrict__ b_gat,
    float* __restrict__ z, unsigned int* __restrict__ zb, int n)
{
    const int wave = blockIdx.x * 4 + __builtin_amdgcn_readfirstlane(threadIdx.x >> 6);
    if (wave >= n) return;
    const int lane = threadIdx.x & 63;
    const int d = wave;
    const int beg = row_ptr[d];
    const int end = row_ptr[d + 1];
    const int c0 = 32 * (lane & 3) + (lane >> 2);
    const int c1 = c0 + 16;
    const int h0 = 2 * (lane & 3);
    const int h1 = h0 + 1;
    const int jm = lane >> 3;      // edge slot this lane scores (within 8)
    const int hm = lane & 7;       // head this lane scores
    const float adst_hm = a_dst[d * 8 + hm];

    float ls0a = 0.f, ls0b = 0.f, ls1a = 0.f, ls1b = 0.f;
    float axa = 0.f, axb = 0.f, aya = 0.f, ayb = 0.f;

    for (int i = beg; i < end; i += 16) {
        // two score rounds: edges i+jm and i+8+jm
        const int idx0 = (i + jm < end) ? (i + jm) : (end - 1);
        const int idx1 = (i + 8 + jm < end) ? (i + 8 + jm) : (end - 1);
        const int sm0 = csr_src[idx0];
        const int sm1 = csr_src[idx1];
        float v0 = a_src[(size_t)sm0 * 8 + hm] + adst_hm;
        float v1 = a_src[(size_t)sm1 * 8 + hm] + adst_hm;
        v0 = (v0 > 0.f) ? v0 : 0.2f * v0;
        v1 = (v1 > 0.f) ? v1 : 0.2f * v1;
        float e0 = __expf(v0);
        float e1 = __expf(v1);
        if (i + jm >= end) e0 = 0.f;
        if (i + 8 + jm >= end) e1 = 0.f;

        int ss[16];
#pragma unroll
        for (int j = 0; j < 16; ++j) {
            const int idx = (i + j < end) ? (i + j) : (end - 1);
            ss[j] = csr_src[idx];
        }
        unsigned int xv[16];
#pragma unroll
        for (int j = 0; j < 16; ++j)
            xv[j] = reinterpret_cast<const unsigned int*>(xpb + (size_t)ss[j] * 128)[lane];
#pragma unroll
        for (int j = 0; j < 16; ++j) {
            const float es = (j < 8) ? e0 : e1;
            const float p0 = __shfl(es, ((j & 7) << 3) + h0);
            const float p1 = __shfl(es, ((j & 7) << 3) + h1);
            const float cx = __uint_as_float(xv[j] << 16);
            const float cy = __uint_as_float(xv[j] & 0xffff0000u);
            if (j & 1) {
                ls0b += p0; ls1b += p1;
                axb = fmaf(p0, cx, axb);
                ayb = fmaf(p1, cy, ayb);
            } else {
                ls0a += p0; ls1a += p1;
                axa = fmaf(p0, cx, axa);
                aya = fmaf(p1, cy, aya);
            }
        }
    }

    const float inv0 = 1.0f / (ls0a + ls0b + 1e-16f);
    const float inv1 = 1.0f / (ls1a + ls1b + 1e-16f);
    const float ox = (axa + axb) * inv0 + b_gat[c0];
    const float oy = (aya + ayb) * inv1 + b_gat[c1];
    z[(size_t)d * 128 + c0] = ox;
    z[(size_t)d * 128 + c1] = oy;
    zb[(size_t)d * 64 + lane] =
        ((unsigned int)(unsigned short)f2bf(oy) << 16) |
        (unsigned int)(unsigned short)f2bf(ox);
}

// ---------------- G2: z1 = z@W1+b1, z2 = z@W2+b2 via MFMA (A from zb) -------
__global__ __launch_bounds__(256) void g2_mfma_fc(
    const unsigned int* __restrict__ zb,
    const unsigned short* __restrict__ S1, const unsigned short* __restrict__ S2,
    const float* __restrict__ b1, const float* __restrict__ b2,
    float* __restrict__ z1, float* __restrict__ z2, int n)
{
    const int wid  = __builtin_amdgcn_readfirstlane(threadIdx.x >> 6);
    const int lane = threadIdx.x & 63;
    const int lr   = lane & 15;
    const int kg   = lane >> 4;
    const int rowbase = blockIdx.x * 128 + wid * 32;

    bf16x8 afr[2][4];
#pragma unroll
    for (int rt = 0; rt < 2; ++rt) {
        int row = rowbase + rt * 16 + lr;
        row = (row < n) ? row : (n - 1);
        const unsigned short* rp = (const unsigned short*)(zb + (size_t)row * 64) + kg * 8;
#pragma unroll
        for (int ks = 0; ks < 4; ++ks)
            afr[rt][ks] = *reinterpret_cast<const bf16x8*>(rp + ks * 32);
    }

    f32x4 acc1[2][8] = {};
    f32x4 acc2[2][8] = {};
#pragma unroll
    for (int cb = 0; cb < 8; ++cb) {
        const unsigned short* bp1 = S1 + ((size_t)(cb * 4) * 64 + lane) * 8;
        const unsigned short* bp2 = S2 + ((size_t)(cb * 4) * 64 + lane) * 8;
        bf16x8 f1[4], f2v[4];
#pragma unroll
        for (int ks = 0; ks < 4; ++ks) {
            f1[ks]  = *reinterpret_cast<const bf16x8*>(bp1 + (size_t)ks * 512);
            f2v[ks] = *reinterpret_cast<const bf16x8*>(bp2 + (size_t)ks * 512);
        }
#pragma unroll
        for (int ks = 0; ks < 4; ++ks) {
            acc1[0][cb] = __builtin_amdgcn_mfma_f32_16x16x32_bf16(afr[0][ks], f1[ks],  acc1[0][cb], 0, 0, 0);
            acc1[1][cb] = __builtin_amdgcn_mfma_f32_16x16x32_bf16(afr[1][ks], f1[ks],  acc1[1][cb], 0, 0, 0);
            acc2[0][cb] = __builtin_amdgcn_mfma_f32_16x16x32_bf16(afr[0][ks], f2v[ks], acc2[0][cb], 0, 0, 0);
            acc2[1][cb] = __builtin_amdgcn_mfma_f32_16x16x32_bf16(afr[1][ks], f2v[ks], acc2[1][cb], 0, 0, 0);
        }
    }

    float bb1[8], bb2[8];
#pragma unroll
    for (int cb = 0; cb < 8; ++cb) { bb1[cb] = b1[cb * 16 + lr]; bb2[cb] = b2[cb * 16 + lr]; }

#pragma unroll
    for (int rt = 0; rt < 2; ++rt) {
#pragma unroll
        for (int reg = 0; reg < 4; ++reg) {
            const int row = rowbase + rt * 16 + kg * 4 + reg;
            if (row < n) {
                float* o1 = z1 + (size_t)row * 128 + lr;
                float* o2 = z2 + (size_t)row * 128 + lr;
#pragma unroll
                for (int cb = 0; cb < 8; ++cb) {
                    o1[cb * 16] = acc1[rt][cb][reg] + bb1[cb];
                    o2[cb * 16] = acc2[rt][cb][reg] + bb2[cb];
                }
            }
        }
    }
}

// ---------------------------------------------------------------------------
extern "C" void kernel_launch(void* const* d_in, const int* in_sizes, int n_in,
                              void* d_out, int out_size, void* d_ws, size_t ws_size,
                              hipStream_t stream)
{
    const float* x       = (const float*)d_in[0];
    const int*   ei      = (const int*)  d_in[1];
    const float* W_gat   = (const float*)d_in[2];
    const float* att_src = (const float*)d_in[3];
    const float* att_dst = (const float*)d_in[4];
    const float* b_gat   = (const float*)d_in[5];
    const float* W_fc1   = (const float*)d_in[6];
    const float* b_fc1   = (const float*)d_in[7];
    const float* W_fc2   = (const float*)d_in[8];
    const float* b_fc2   = (const float*)d_in[9];

    const int N = in_sizes[0] / 128;
    const int E = in_sizes[1] / 2;
    const int tot = E + N;
    const int nblk = (tot + IPB - 1) / IPB;
    const int nbuck_used = (N + BNODES - 1) >> BSHIFT;
    const int g1b = (N + 127) / 128;

    char* w = (char*)d_ws;
    unsigned short* xpb = (unsigned short*)w;  w += (size_t)N * 128 * 2;
    unsigned int* zb = (unsigned int*)w;       w += (size_t)N * 64 * 4;
    float* a_src  = (float*)w;  w += (size_t)N * 8 * 4;
    float* a_dst  = (float*)w;  w += (size_t)N * 8 * 4;
    int* row_ptr  = (int*)w;    w += (size_t)(N + 1) * 4;
    w = (char*)(((size_t)w + 15) & ~(size_t)15);
    unsigned short* S0 = (unsigned short*)w; w += 16384 * 2;
    unsigned short* S1 = (unsigned short*)w; w += 16384 * 2;
    unsigned short* S2 = (unsigned short*)w; w += 16384 * 2;
    unsigned short* Sa = (unsigned short*)w; w += 2048 * 2;
    int* M          = (int*)w;  w += (size_t)nblk * NBUCK * 4;
    int* col_total  = (int*)w;  w += NBUCK * 4;
    int* bucket_ptr = (int*)w;  w += (NBUCK + 1) * 4;
    w = (char*)(((size_t)w + 15) & ~(size_t)15);
    int* pairs    = (int*)w;    w += (size_t)tot * 4;
    int* csr_src  = (int*)w;    w += (size_t)tot * 4;

    float* z  = (float*)d_out;
    float* z1 = z  + (size_t)N * 128;
    float* z2 = z1 + (size_t)N * 128;

    k0_swizzle<<<(3 * 2048 + 256 + 255) / 256, 256, 0, stream>>>(
        W_gat, W_fc1, W_fc2, att_src, att_dst, S0, S1, S2, Sa, col_total);

    g1p1<<<g1b + nblk, 256, 0, stream>>>(x, S0, Sa, xpb, a_src, a_dst,
                                         ei, M, col_total, N, E, g1b, nblk);

    p2a_colscan<<<NBUCK, 256, 0, stream>>>(M, col_total, bucket_ptr, row_ptr, nblk, N);
    p3_scatter<<<nblk, 256, 0, stream>>>(ei, M, pairs, E, N, nblk);
    p4_finalize<<<nbuck_used, 256, 0, stream>>>(pairs, bucket_ptr, row_ptr, csr_src, N);

    k5_aggregate<<<(N + 3) / 4, 256, 0, stream>>>(xpb, a_src, a_dst, row_ptr, csr_src,
                                                  b_gat, z, zb, N);

    g2_mfma_fc<<<(N + 127) / 128, 256, 0, stream>>>(zb, S1, S2, b_fc1, b_fc2, z1, z2, N);
}

// Round 14
// 204.430 us; speedup vs baseline: 1.0218x; 1.0218x over previous
//
#include <hip/hip_runtime.h>
#include <hip/hip_bf16.h>

// ---------------------------------------------------------------------------
// GAT + 2 FC layers, MFMA + atomic-free CSR build (7 launches).
// xpb uses a PERMUTED channel layout (word w of a row = channels
// c0=32(w&3)+(w>>2), c1=c0+16) so g1's MFMA D-fragment stores are coalesced
// int4 writes. k5 consumes the permutation natively; zb inherits it and
// k0 applies the same k-permutation to W_fc1/W_fc2 rows (GEMM is invariant
// to a shared contraction-index permutation).
// k5: lane-specialized scores, MLP=8 (empirical optimum: r10/r11 87.6us;
// MLP=16 regressed to 93.4us via occupancy loss).
// ---------------------------------------------------------------------------

#define NBUCK  256
#define BSHIFT 9
#define BNODES 512
#define IPB    8192

typedef __attribute__((ext_vector_type(8))) short bf16x8;
typedef __attribute__((ext_vector_type(4))) float f32x4;

static __device__ __forceinline__ short f2bf(float f) {
    __hip_bfloat16 h = __float2bfloat16(f);
    return *reinterpret_cast<short*>(&h);
}

// ---------------- K0: weight swizzles + WA precompute + col_total zero -------
__global__ __launch_bounds__(256) void k0_swizzle(
    const float* __restrict__ W0, const float* __restrict__ W1,
    const float* __restrict__ W2, const float* __restrict__ att_s,
    const float* __restrict__ att_d, unsigned short* __restrict__ S0,
    unsigned short* __restrict__ S1, unsigned short* __restrict__ S2,
    unsigned short* __restrict__ Sa, int* __restrict__ col_total)
{
    const int t = blockIdx.x * 256 + threadIdx.x;
    if (t < NBUCK) col_total[t] = 0;
    if (t < 3 * 2048) {
        const int m = t >> 11;
        const int r = t & 2047;
        const int tile = r >> 6;          // cb*4 + ks
        const int l    = r & 63;
        const int ks   = tile & 3;
        const int cb   = tile >> 2;
        const int c    = cb * 16 + (l & 15);
        const int kb   = ks * 32 + (l >> 4) * 8;
        const float* W = (m == 0) ? W0 : (m == 1) ? W1 : W2;
        unsigned short* S = (m == 0) ? S0 : (m == 1) ? S1 : S2;
        unsigned short* dst = S + ((size_t)tile * 64 + l) * 8;
#pragma unroll
        for (int j = 0; j < 8; ++j) {
            const int p = kb + j;
            int krow;
            if (m == 0) {
                krow = p;                         // g1: A from x, canonical k
            } else {
                // zb's permuted k-order: word w=p>>1, half hi=p&1
                const int w2 = p >> 1, hi = p & 1;
                krow = 32 * (w2 & 3) + (w2 >> 2) + 16 * hi;
            }
            dst[j] = (unsigned short)f2bf(W[krow * 128 + c]);
        }
    } else if (t < 3 * 2048 + 256) {
        const int r  = t - 3 * 2048;
        const int ks = r >> 6;
        const int l  = r & 63;
        const int hp = l & 15;
        const int h  = hp & 7;
        const float* av = (hp < 8) ? (att_s + h * 16) : (att_d + h * 16);
        unsigned short* dst = Sa + ((size_t)ks * 64 + l) * 8;
#pragma unroll
        for (int j = 0; j < 8; ++j) {
            const int k = ks * 32 + (l >> 4) * 8 + j;
            float acc = 0.f;
#pragma unroll
            for (int u = 0; u < 16; ++u)
                acc += W0[k * 128 + h * 16 + u] * av[u];
            dst[j] = (unsigned short)f2bf(acc);
        }
    }
}

// ---------------- G1P1: fused GEMM+scores | bucket histogram ----------------
__global__ __launch_bounds__(256) void g1p1(
    const float* __restrict__ x, const unsigned short* __restrict__ Wswz,
    const unsigned short* __restrict__ Sa, unsigned short* __restrict__ xpb,
    float* __restrict__ a_src, float* __restrict__ a_dst,
    const int* __restrict__ ei, int* __restrict__ M, int* __restrict__ col_total,
    int n, int E, int g1b, int nblk)
{
    if ((int)blockIdx.x < g1b) {
        const int wid  = __builtin_amdgcn_readfirstlane(threadIdx.x >> 6);
        const int lane = threadIdx.x & 63;
        const int lr   = lane & 15;
        const int kg   = lane >> 4;
        const int rowbase = blockIdx.x * 128 + wid * 32;

        bf16x8 afr[2][4];
#pragma unroll
        for (int rt = 0; rt < 2; ++rt) {
            int row = rowbase + rt * 16 + lr;
            row = (row < n) ? row : (n - 1);
            const float* rp = x + (size_t)row * 128 + kg * 8;
#pragma unroll
            for (int ks = 0; ks < 4; ++ks) {
                const float4 v0 = *reinterpret_cast<const float4*>(rp + ks * 32);
                const float4 v1 = *reinterpret_cast<const float4*>(rp + ks * 32 + 4);
                bf16x8 a;
                a[0] = f2bf(v0.x); a[1] = f2bf(v0.y); a[2] = f2bf(v0.z); a[3] = f2bf(v0.w);
                a[4] = f2bf(v1.x); a[5] = f2bf(v1.y); a[6] = f2bf(v1.z); a[7] = f2bf(v1.w);
                afr[rt][ks] = a;
            }
        }

        f32x4 acc[2][8] = {};
#pragma unroll
        for (int cb = 0; cb < 8; ++cb) {
            const unsigned short* bp = Wswz + ((size_t)(cb * 4) * 64 + lane) * 8;
            bf16x8 bfr[4];
#pragma unroll
            for (int ks = 0; ks < 4; ++ks)
                bfr[ks] = *reinterpret_cast<const bf16x8*>(bp + (size_t)ks * 512);
#pragma unroll
            for (int ks = 0; ks < 4; ++ks) {
                acc[0][cb] = __builtin_amdgcn_mfma_f32_16x16x32_bf16(afr[0][ks], bfr[ks], acc[0][cb], 0, 0, 0);
                acc[1][cb] = __builtin_amdgcn_mfma_f32_16x16x32_bf16(afr[1][ks], bfr[ks], acc[1][cb], 0, 0, 0);
            }
        }

        f32x4 accs[2] = {};
#pragma unroll
        for (int ks = 0; ks < 4; ++ks) {
            const bf16x8 bs = *reinterpret_cast<const bf16x8*>(Sa + ((size_t)ks * 64 + lane) * 8);
            accs[0] = __builtin_amdgcn_mfma_f32_16x16x32_bf16(afr[0][ks], bs, accs[0], 0, 0, 0);
            accs[1] = __builtin_amdgcn_mfma_f32_16x16x32_bf16(afr[1][ks], bs, accs[1], 0, 0, 0);
        }

#pragma unroll
        for (int rt = 0; rt < 2; ++rt) {
#pragma unroll
            for (int reg = 0; reg < 4; ++reg) {
                const int row = rowbase + rt * 16 + kg * 4 + reg;
                if (row < n) {
                    int4 pk;
                    pk.x = (int)(((unsigned)(unsigned short)f2bf(acc[rt][1][reg]) << 16) |
                                  (unsigned)(unsigned short)f2bf(acc[rt][0][reg]));
                    pk.y = (int)(((unsigned)(unsigned short)f2bf(acc[rt][3][reg]) << 16) |
                                  (unsigned)(unsigned short)f2bf(acc[rt][2][reg]));
                    pk.z = (int)(((unsigned)(unsigned short)f2bf(acc[rt][5][reg]) << 16) |
                                  (unsigned)(unsigned short)f2bf(acc[rt][4][reg]));
                    pk.w = (int)(((unsigned)(unsigned short)f2bf(acc[rt][7][reg]) << 16) |
                                  (unsigned)(unsigned short)f2bf(acc[rt][6][reg]));
                    *reinterpret_cast<int4*>(xpb + (size_t)row * 128 + lr * 8) = pk;
                    if (lr < 8) a_src[row * 8 + lr] = accs[rt][reg];
                    else        a_dst[row * 8 + (lr - 8)] = accs[rt][reg];
                }
            }
        }
    } else {
        __shared__ int h[NBUCK];
        const int pb  = blockIdx.x - g1b;
        const int tid = threadIdx.x;
        for (int k = tid; k < NBUCK; k += 256) h[k] = 0;
        __syncthreads();

        const int tot = E + n;
        const int base = pb * IPB;
        const int lim = (base + IPB < tot) ? base + IPB : tot;
        for (int j = base + tid; j < lim; j += 256) {
            const int d = (j < E) ? ei[E + j] : (j - E);
            atomicAdd(&h[d >> BSHIFT], 1);
        }
        __syncthreads();
        for (int k = tid; k < NBUCK; k += 256) {
            M[(size_t)k * nblk + pb] = h[k];
            if (h[k]) atomicAdd(&col_total[k], h[k]);
        }
    }
}

// ---------------- P2a: bucket bases + per-bucket scan of M ----------------
__global__ __launch_bounds__(256) void p2a_colscan(
    int* __restrict__ M, const int* __restrict__ col_total,
    int* __restrict__ bucket_ptr, int* __restrict__ row_ptr, int nblk, int N)
{
    const int b    = blockIdx.x;
    const int tid  = threadIdx.x;
    const int lane = tid & 63;
    const int wid  = tid >> 6;
    __shared__ int wsum[4];
    __shared__ int sbase;

    const int v0 = col_total[tid];
    int ws0 = v0;
#pragma unroll
    for (int off = 1; off < 64; off <<= 1) {
        const int t = __shfl_up(ws0, off);
        if (lane >= off) ws0 += t;
    }
    if (lane == 63) wsum[wid] = ws0;
    __syncthreads();
    int woff0 = 0;
    for (int w2 = 0; w2 < wid; ++w2) woff0 += wsum[w2];
    const int excl0 = woff0 + ws0 - v0;
    if (tid == b) sbase = excl0;
    if (b == NBUCK - 1 && tid == NBUCK - 1) {
        bucket_ptr[NBUCK] = excl0 + v0;
        row_ptr[N] = excl0 + v0;
    }
    __syncthreads();
    const int base = sbase;
    if (tid == 0) bucket_ptr[b] = base;
    __syncthreads();

    int carry = base;
    for (int bb = 0; bb < nblk; bb += 256) {
        const int idx = bb + tid;
        const int v = (idx < nblk) ? M[(size_t)b * nblk + idx] : 0;
        int ws = v;
#pragma unroll
        for (int off = 1; off < 64; off <<= 1) {
            const int t = __shfl_up(ws, off);
            if (lane >= off) ws += t;
        }
        if (lane == 63) wsum[wid] = ws;
        __syncthreads();
        int woff = 0;
        for (int w2 = 0; w2 < wid; ++w2) woff += wsum[w2];
        const int alltot = wsum[0] + wsum[1] + wsum[2] + wsum[3];
        if (idx < nblk) M[(size_t)b * nblk + idx] = carry + woff + ws - v;
        carry += alltot;
        __syncthreads();
    }
}

// ---------------- P3: scatter packed (src | dl<<17) into bucket segments -----
__global__ __launch_bounds__(256) void p3_scatter(
    const int* __restrict__ ei, const int* __restrict__ M,
    int* __restrict__ pairs, int E, int N, int nblk)
{
    __shared__ int lcnt[NBUCK];
    const int tid = threadIdx.x;
    for (int k = tid; k < NBUCK; k += 256) lcnt[k] = 0;
    __syncthreads();

    const int tot = E + N;
    const int base = blockIdx.x * IPB;
    const int lim = (base + IPB < tot) ? base + IPB : tot;
    for (int j = base + tid; j < lim; j += 256) {
        int s, d;
        if (j < E) { s = ei[j]; d = ei[E + j]; }
        else       { s = j - E; d = s; }
        const int b = d >> BSHIFT;
        const int r = atomicAdd(&lcnt[b], 1);
        const int pos = M[(size_t)b * nblk + blockIdx.x] + r;
        pairs[pos] = s | ((d & (BNODES - 1)) << 17);
    }
}

// ---------------- P4: per-bucket row_ptr + csr scatter ----------------
__global__ __launch_bounds__(256) void p4_finalize(
    const int* __restrict__ pairs, const int* __restrict__ bucket_ptr,
    int* __restrict__ row_ptr, int* __restrict__ csr_src, int N)
{
    const int b     = blockIdx.x;
    const int node0 = b << BSHIFT;
    const int beg   = bucket_ptr[b];
    const int end   = bucket_ptr[b + 1];
    const int tid   = threadIdx.x;
    const int lane  = tid & 63;
    const int wid   = tid >> 6;

    __shared__ int hist[BNODES];
    __shared__ int exc[BNODES];
    __shared__ int cnt2[BNODES];
    __shared__ int wsum[4];

    for (int k = tid; k < BNODES; k += 256) { hist[k] = 0; cnt2[k] = 0; }
    __syncthreads();

    for (int i = beg + tid; i < end; i += 256)
        atomicAdd(&hist[pairs[i] >> 17], 1);
    __syncthreads();

    const int a0 = hist[2 * tid];
    const int a1 = hist[2 * tid + 1];
    const int s  = a0 + a1;
    int ws = s;
#pragma unroll
    for (int off = 1; off < 64; off <<= 1) {
        const int t = __shfl_up(ws, off);
        if (lane >= off) ws += t;
    }
    if (lane == 63) wsum[wid] = ws;
    __syncthreads();
    int woff = 0;
    for (int w2 = 0; w2 < wid; ++w2) woff += wsum[w2];
    const int e0 = woff + ws - s;
    exc[2 * tid]     = e0;
    exc[2 * tid + 1] = e0 + a0;
    __syncthreads();

    for (int k = tid; k < BNODES; k += 256) {
        const int node = node0 + k;
        if (node < N) row_ptr[node] = beg + exc[k];
    }
    for (int i = beg + tid; i < end; i += 256) {
        const int v  = pairs[i];
        const int dl = v >> 17;
        const int r  = atomicAdd(&cnt2[dl], 1);
        csr_src[beg + exc[dl] + r] = v & 0x1FFFF;
    }
}

// ---------------- K5: aggregation, lane-specialized scores, permuted layout --
__global__ __launch_bounds__(256) void k5_aggregate(
    const unsigned short* __restrict__ xpb, const float* __restrict__ a_src,
    const float* __restrict__ a_dst, const int* __restrict__ row_ptr,
    const int* __restrict__ csr_src, const float* __restrict__ b_gat,
    float* __restrict__ z, unsigned int* __restrict__ zb, int n)
{
    const int wave = blockIdx.x * 4 + __builtin_amdgcn_readfirstlane(threadIdx.x >> 6);
    if (wave >= n) return;
    const int lane = threadIdx.x & 63;
    const int d = wave;
    const int beg = row_ptr[d];
    const int end = row_ptr[d + 1];
    // permuted word -> channels
    const int c0 = 32 * (lane & 3) + (lane >> 2);
    const int c1 = c0 + 16;
    const int h0 = 2 * (lane & 3);
    const int h1 = h0 + 1;
    const int jm = lane >> 3;      // edge slot this lane scores
    const int hm = lane & 7;       // head this lane scores
    const float adst_hm = a_dst[d * 8 + hm];

    float ls0a = 0.f, ls0b = 0.f, ls1a = 0.f, ls1b = 0.f;
    float axa = 0.f, axb = 0.f, aya = 0.f, ayb = 0.f;

    for (int i = beg; i < end; i += 8) {
        const int idxm = (i + jm < end) ? (i + jm) : (end - 1);
        const int sm = csr_src[idxm];
        float v = a_src[(size_t)sm * 8 + hm] + adst_hm;
        v = (v > 0.f) ? v : 0.2f * v;
        float e = __expf(v);
        if (i + jm >= end) e = 0.f;

        int ss[8];
#pragma unroll
        for (int j = 0; j < 8; ++j) {
            const int idx = (i + j < end) ? (i + j) : (end - 1);
            ss[j] = csr_src[idx];
        }
        unsigned int xv[8];
#pragma unroll
        for (int j = 0; j < 8; ++j)
            xv[j] = reinterpret_cast<const unsigned int*>(xpb + (size_t)ss[j] * 128)[lane];
#pragma unroll
        for (int j = 0; j < 8; ++j) {
            const float p0 = __shfl(e, (j << 3) + h0);
            const float p1 = __shfl(e, (j << 3) + h1);
            const float cx = __uint_as_float(xv[j] << 16);
            const float cy = __uint_as_float(xv[j] & 0xffff0000u);
            if (j & 1) {
                ls0b += p0; ls1b += p1;
                axb = fmaf(p0, cx, axb);
                ayb = fmaf(p1, cy, ayb);
            } else {
                ls0a += p0; ls1a += p1;
                axa = fmaf(p0, cx, axa);
                aya = fmaf(p1, cy, aya);
            }
        }
    }

    const float inv0 = 1.0f / (ls0a + ls0b + 1e-16f);
    const float inv1 = 1.0f / (ls1a + ls1b + 1e-16f);
    const float ox = (axa + axb) * inv0 + b_gat[c0];
    const float oy = (aya + ayb) * inv1 + b_gat[c1];
    z[(size_t)d * 128 + c0] = ox;
    z[(size_t)d * 128 + c1] = oy;
    zb[(size_t)d * 64 + lane] =
        ((unsigned int)(unsigned short)f2bf(oy) << 16) |
        (unsigned int)(unsigned short)f2bf(ox);
}

// ---------------- G2: z1 = z@W1+b1, z2 = z@W2+b2 via MFMA (A from zb) -------
__global__ __launch_bounds__(256) void g2_mfma_fc(
    const unsigned int* __restrict__ zb,
    const unsigned short* __restrict__ S1, const unsigned short* __restrict__ S2,
    const float* __restrict__ b1, const float* __restrict__ b2,
    float* __restrict__ z1, float* __restrict__ z2, int n)
{
    const int wid  = __builtin_amdgcn_readfirstlane(threadIdx.x >> 6);
    const int lane = threadIdx.x & 63;
    const int lr   = lane & 15;
    const int kg   = lane >> 4;
    const int rowbase = blockIdx.x * 128 + wid * 32;

    bf16x8 afr[2][4];
#pragma unroll
    for (int rt = 0; rt < 2; ++rt) {
        int row = rowbase + rt * 16 + lr;
        row = (row < n) ? row : (n - 1);
        const unsigned short* rp = (const unsigned short*)(zb + (size_t)row * 64) + kg * 8;
#pragma unroll
        for (int ks = 0; ks < 4; ++ks)
            afr[rt][ks] = *reinterpret_cast<const bf16x8*>(rp + ks * 32);
    }

    f32x4 acc1[2][8] = {};
    f32x4 acc2[2][8] = {};
#pragma unroll
    for (int cb = 0; cb < 8; ++cb) {
        const unsigned short* bp1 = S1 + ((size_t)(cb * 4) * 64 + lane) * 8;
        const unsigned short* bp2 = S2 + ((size_t)(cb * 4) * 64 + lane) * 8;
        bf16x8 f1[4], f2v[4];
#pragma unroll
        for (int ks = 0; ks < 4; ++ks) {
            f1[ks]  = *reinterpret_cast<const bf16x8*>(bp1 + (size_t)ks * 512);
            f2v[ks] = *reinterpret_cast<const bf16x8*>(bp2 + (size_t)ks * 512);
        }
#pragma unroll
        for (int ks = 0; ks < 4; ++ks) {
            acc1[0][cb] = __builtin_amdgcn_mfma_f32_16x16x32_bf16(afr[0][ks], f1[ks],  acc1[0][cb], 0, 0, 0);
            acc1[1][cb] = __builtin_amdgcn_mfma_f32_16x16x32_bf16(afr[1][ks], f1[ks],  acc1[1][cb], 0, 0, 0);
            acc2[0][cb] = __builtin_amdgcn_mfma_f32_16x16x32_bf16(afr[0][ks], f2v[ks], acc2[0][cb], 0, 0, 0);
            acc2[1][cb] = __builtin_amdgcn_mfma_f32_16x16x32_bf16(afr[1][ks], f2v[ks], acc2[1][cb], 0, 0, 0);
        }
    }

    float bb1[8], bb2[8];
#pragma unroll
    for (int cb = 0; cb < 8; ++cb) { bb1[cb] = b1[cb * 16 + lr]; bb2[cb] = b2[cb * 16 + lr]; }

#pragma unroll
    for (int rt = 0; rt < 2; ++rt) {
#pragma unroll
        for (int reg = 0; reg < 4; ++reg) {
            const int row = rowbase + rt * 16 + kg * 4 + reg;
            if (row < n) {
                float* o1 = z1 + (size_t)row * 128 + lr;
                float* o2 = z2 + (size_t)row * 128 + lr;
#pragma unroll
                for (int cb = 0; cb < 8; ++cb) {
                    o1[cb * 16] = acc1[rt][cb][reg] + bb1[cb];
                    o2[cb * 16] = acc2[rt][cb][reg] + bb2[cb];
                }
            }
        }
    }
}

// ---------------------------------------------------------------------------
extern "C" void kernel_launch(void* const* d_in, const int* in_sizes, int n_in,
                              void* d_out, int out_size, void* d_ws, size_t ws_size,
                              hipStream_t stream)
{
    const float* x       = (const float*)d_in[0];
    const int*   ei      = (const int*)  d_in[1];
    const float* W_gat   = (const float*)d_in[2];
    const float* att_src = (const float*)d_in[3];
    const float* att_dst = (const float*)d_in[4];
    const float* b_gat   = (const float*)d_in[5];
    const float* W_fc1   = (const float*)d_in[6];
    const float* b_fc1   = (const float*)d_in[7];
    const float* W_fc2   = (const float*)d_in[8];
    const float* b_fc2   = (const float*)d_in[9];

    const int N = in_sizes[0] / 128;
    const int E = in_sizes[1] / 2;
    const int tot = E + N;
    const int nblk = (tot + IPB - 1) / IPB;
    const int nbuck_used = (N + BNODES - 1) >> BSHIFT;
    const int g1b = (N + 127) / 128;

    char* w = (char*)d_ws;
    unsigned short* xpb = (unsigned short*)w;  w += (size_t)N * 128 * 2;
    unsigned int* zb = (unsigned int*)w;       w += (size_t)N * 64 * 4;
    float* a_src  = (float*)w;  w += (size_t)N * 8 * 4;
    float* a_dst  = (float*)w;  w += (size_t)N * 8 * 4;
    int* row_ptr  = (int*)w;    w += (size_t)(N + 1) * 4;
    w = (char*)(((size_t)w + 15) & ~(size_t)15);
    unsigned short* S0 = (unsigned short*)w; w += 16384 * 2;
    unsigned short* S1 = (unsigned short*)w; w += 16384 * 2;
    unsigned short* S2 = (unsigned short*)w; w += 16384 * 2;
    unsigned short* Sa = (unsigned short*)w; w += 2048 * 2;
    int* M          = (int*)w;  w += (size_t)nblk * NBUCK * 4;
    int* col_total  = (int*)w;  w += NBUCK * 4;
    int* bucket_ptr = (int*)w;  w += (NBUCK + 1) * 4;
    w = (char*)(((size_t)w + 15) & ~(size_t)15);
    int* pairs    = (int*)w;    w += (size_t)tot * 4;
    int* csr_src  = (int*)w;    w += (size_t)tot * 4;

    float* z  = (float*)d_out;
    float* z1 = z  + (size_t)N * 128;
    float* z2 = z1 + (size_t)N * 128;

    k0_swizzle<<<(3 * 2048 + 256 + 255) / 256, 256, 0, stream>>>(
        W_gat, W_fc1, W_fc2, att_src, att_dst, S0, S1, S2, Sa, col_total);

    g1p1<<<g1b + nblk, 256, 0, stream>>>(x, S0, Sa, xpb, a_src, a_dst,
                                         ei, M, col_total, N, E, g1b, nblk);

    p2a_colscan<<<NBUCK, 256, 0, stream>>>(M, col_total, bucket_ptr, row_ptr, nblk, N);
    p3_scatter<<<nblk, 256, 0, stream>>>(ei, M, pairs, E, N, nblk);
    p4_finalize<<<nbuck_used, 256, 0, stream>>>(pairs, bucket_ptr, row_ptr, csr_src, N);

    k5_aggregate<<<(N + 3) / 4, 256, 0, stream>>>(xpb, a_src, a_dst, row_ptr, csr_src,
                                                  b_gat, z, zb, N);

    g2_mfma_fc<<<(N + 127) / 128, 256, 0, stream>>>(zb, S1, S2, b_fc1, b_fc2, z1, z2, N);
}